// Round 16
// baseline (64.943 us; speedup 1.0000x reference)
//
#include <hip/hip_runtime.h>
#include <math.h>

static constexpr int N   = 4096;  // IN_SIZE
static constexpr int H   = 5;     // HID
static constexpr int NO  = 2048;  // OUT_SIZE
static constexpr float FEPS = 1e-4f;
static constexpr int NJC  = 4;          // j-chunks (1024 cols each)
static constexpr int NIG  = 128;        // i-groups (32 rows each)
static constexpr int RPB  = N / NIG;    // 32 rows per block
static constexpr int NBLK = NIG * NJC;  // 512 partial-M blocks (2/CU)
static constexpr int NCON = 256;        // k_out blocks
static constexpr int NR   = NO / NCON;  // 8 output rows per k_out block
static constexpr int GRP  = 8;          // prefetch depth (rows)

#if __has_builtin(__builtin_amdgcn_rcpf)
__device__ __forceinline__ float frcp(float x) { return __builtin_amdgcn_rcpf(x); }
#else
__device__ __forceinline__ float frcp(float x) { return 1.0f / x; }
#endif
#if __has_builtin(__builtin_amdgcn_rsqf)
__device__ __forceinline__ float frsq(float x) { return __builtin_amdgcn_rsqf(x); }
#else
__device__ __forceinline__ float frsq(float x) { return 1.0f / sqrtf(x); }
#endif

__device__ __forceinline__ float wave_reduce(float v) {
#pragma unroll
    for (int o = 32; o > 0; o >>= 1) v += __shfl_down(v, o, 64);
    return v;
}

// K1: 2-D tiled partial of M[a][b] = sum_{i,j} W1[i,a] X[i,j] W1[j,b].
// R13 geometry (512 blocks, 32 rows x 1024-col j-chunk per block) PLUS an
// explicit 8-deep double-buffered X prefetch: 8 outstanding 16B loads per
// thread x 8 waves/CU = 256 in flight per CU -> L3 latency (~500cy) hidden;
// remaining cost is the ~8us VMEM issue floor + ~2.4us VALU.
__global__ __launch_bounds__(256) void k_xw1(const float* __restrict__ X,
                                             const float* __restrict__ W1,
                                             float* __restrict__ Mp) {
    const int b   = blockIdx.x;
    const int ig  = b >> 2;        // 128 i-groups
    const int jcb = b & 3;         // 4 j-chunks
    const int t   = threadIdx.x;
    const int j4  = jcb * 256 + t; // this thread's float4 column
    const float4* W14 = reinterpret_cast<const float4*>(W1);
    const float4* X4  = reinterpret_cast<const float4*>(X);

    float wf[20];
    {
        const float4 f0 = W14[5 * j4 + 0];
        const float4 f1 = W14[5 * j4 + 1];
        const float4 f2 = W14[5 * j4 + 2];
        const float4 f3 = W14[5 * j4 + 3];
        const float4 f4 = W14[5 * j4 + 4];
        wf[0]=f0.x;  wf[1]=f0.y;  wf[2]=f0.z;  wf[3]=f0.w;
        wf[4]=f1.x;  wf[5]=f1.y;  wf[6]=f1.z;  wf[7]=f1.w;
        wf[8]=f2.x;  wf[9]=f2.y;  wf[10]=f2.z; wf[11]=f2.w;
        wf[12]=f3.x; wf[13]=f3.y; wf[14]=f3.z; wf[15]=f3.w;
        wf[16]=f4.x; wf[17]=f4.y; wf[18]=f4.z; wf[19]=f4.w;
    }

    float pm[H][H];
#pragma unroll
    for (int a = 0; a < H; ++a)
#pragma unroll
        for (int bb = 0; bb < H; ++bb) pm[a][bb] = 0.f;

    const int i0 = ig * RPB;

    // prologue: prefetch group 0 (8 rows)
    float4 xr[GRP];
#pragma unroll
    for (int k = 0; k < GRP; ++k)
        xr[k] = X4[(size_t)(i0 + k) * (N / 4) + j4];

#pragma unroll
    for (int g = 0; g < RPB / GRP; ++g) {
        // issue next group's loads (independent, fill the pipe)
        float4 xn[GRP];
        if (g < RPB / GRP - 1) {
#pragma unroll
            for (int k = 0; k < GRP; ++k)
                xn[k] = X4[(size_t)(i0 + (g + 1) * GRP + k) * (N / 4) + j4];
        }
        // consume current group
#pragma unroll
        for (int k = 0; k < GRP; ++k) {
            const int   row = i0 + g * GRP + k;
            const float4 x  = xr[k];
            float t5[H];
#pragma unroll
            for (int a = 0; a < H; ++a)
                t5[a] = x.x * wf[a]      + x.y * wf[5 + a]
                      + x.z * wf[10 + a] + x.w * wf[15 + a];
            float w1r[H];
#pragma unroll
            for (int a = 0; a < H; ++a) w1r[a] = W1[(size_t)row * H + a];
#pragma unroll
            for (int a = 0; a < H; ++a)
#pragma unroll
                for (int bb = 0; bb < H; ++bb) pm[a][bb] += w1r[a] * t5[bb];
        }
        if (g < RPB / GRP - 1) {
#pragma unroll
            for (int k = 0; k < GRP; ++k) xr[k] = xn[k];
        }
    }

    __shared__ float sm[4][25];
    {
        const int lane = t & 63, wv = t >> 6;
#pragma unroll
        for (int a = 0; a < H; ++a)
#pragma unroll
            for (int bb = 0; bb < H; ++bb) {
                const float v = wave_reduce(pm[a][bb]);
                if (lane == 0) sm[wv][a * H + bb] = v;
            }
    }
    __syncthreads();
    if (t < 25)
        Mp[b * 25 + t] = sm[0][t] + sm[1][t] + sm[2][t] + sm[3][t];
}

// Lane-parallel Jacobi rotation, compile-time (p,q). Lane L (<25) holds
// a = A[L/5][L%5], u = U[L/5][L%5].
#define JROT(p, q)                                                            \
    {                                                                         \
        const float apq = __shfl(a, (p) * 5 + (q), 64);                       \
        const float app = __shfl(a, (p) * 5 + (p), 64);                       \
        const float aqq = __shfl(a, (q) * 5 + (q), 64);                       \
        const bool  skip =                                                    \
            (apq * apq) <= (1e-26f * (app * app + aqq * aqq) + 1e-38f);       \
        const float theta = (aqq - app) * frcp(2.0f * apq);                   \
        const float tden  = fabsf(theta) + sqrtf(theta * theta + 1.0f);       \
        const float ttv   = ((theta >= 0.0f) ? 1.0f : -1.0f) * frcp(tden);    \
        float cc = frsq(ttv * ttv + 1.0f);                                    \
        float ss = ttv * cc;                                                  \
        cc = skip ? 1.0f : cc;                                                \
        ss = skip ? 0.0f : ss;                                                \
        {                                                                     \
            const int  pr   = ((r == (p)) ? (q) : ((r == (q)) ? (p) : r));    \
            const float prt = __shfl(a, pr * 5 + c, 64);                      \
            a = (r == (p)) ? (cc * a - ss * prt)                              \
                           : ((r == (q)) ? (ss * prt + cc * a) : a);          \
        }                                                                     \
        {                                                                     \
            const int  pc   = ((c == (p)) ? (q) : ((c == (q)) ? (p) : c));    \
            const float prt = __shfl(a, r * 5 + pc, 64);                      \
            a = (c == (p)) ? (cc * a - ss * prt)                              \
                           : ((c == (q)) ? (ss * prt + cc * a) : a);          \
            const float urt = __shfl(u, r * 5 + pc, 64);                      \
            u = (c == (p)) ? (cc * u - ss * urt)                              \
                           : ((c == (q)) ? (ss * urt + cc * u) : u);          \
        }                                                                     \
    }

// K2: 256 blocks, NR=8 output rows each. Redundant reduce+Jacobi per block
// (concurrent across blocks -> hidden), then streaming W2 -> Z epilogue.
__global__ __launch_bounds__(256) void k_out(const float* __restrict__ Mp,
                                             const float* __restrict__ W2,
                                             float* __restrict__ Z) {
    __shared__ float sred[10][26];
    __shared__ float Msum[25];
    __shared__ float ys[25];
    const int t = threadIdx.x;

    if (t < 250) {
        const int e = t % 25, g = t / 25;
        float s = 0.f;
#pragma unroll 8
        for (int p = g; p < NBLK; p += 10) s += Mp[p * 25 + e];
        sred[g][e] = s;
    }
    __syncthreads();
    if (t < 25) {
        float s = 0.f;
#pragma unroll
        for (int g = 0; g < 10; ++g) s += sred[g][t];
        Msum[t] = s;
    }
    __syncthreads();

    if (t < 64) {
        const int r = t / 5, c = t % 5;
        const float m = (t < 25) ? Msum[t] : 0.f;
        float a = 0.f;
#pragma unroll
        for (int k = 0; k < H; ++k)
            a += __shfl(m, r * 5 + k, 64) * __shfl(m, c * 5 + k, 64);
        float u = (t < 25 && r == c) ? 1.0f : 0.0f;

        for (int sweep = 0; sweep < 6; ++sweep) {
            JROT(0, 1) JROT(0, 2) JROT(0, 3) JROT(0, 4) JROT(1, 2)
            JROT(1, 3) JROT(1, 4) JROT(2, 3) JROT(2, 4) JROT(3, 4)
        }

        const float ev = fmaxf(sqrtf(fmaxf(a, 0.0f)), FEPS);
        float yv = 0.f;
#pragma unroll
        for (int k = 0; k < H; ++k) {
            const float evk = __shfl(ev, 6 * k, 64);
            const float urk = __shfl(u, r * 5 + k, 64);
            const float uck = __shfl(u, c * 5 + k, 64);
            yv += evk * urk * uck;
        }
        if (t < 25) ys[t] = yv - ((r == c) ? FEPS : 0.f);
    }
    __syncthreads();

    const int i0 = blockIdx.x * NR;
    float cmat[NR][H];
#pragma unroll
    for (int r = 0; r < NR; ++r) {
        float wcol[H];
#pragma unroll
        for (int k = 0; k < H; ++k) wcol[k] = W2[(size_t)k * NO + i0 + r];
#pragma unroll
        for (int m = 0; m < H; ++m) {
            float s = 0.f;
#pragma unroll
            for (int k = 0; k < H; ++k) s += wcol[k] * ys[k * H + m];
            cmat[r][m] = s;
        }
    }

#pragma unroll
    for (int hh = 0; hh < 2; ++hh) {
        const int jj = (hh * 256 + t) * 4;
        float4 w2j[H];
#pragma unroll
        for (int m = 0; m < H; ++m)
            w2j[m] = *reinterpret_cast<const float4*>(W2 + (size_t)m * NO + jj);
#pragma unroll
        for (int r = 0; r < NR; ++r) {
            const int i = i0 + r;
            float zx = 0.f, zy = 0.f, zz = 0.f, zw = 0.f;
#pragma unroll
            for (int m = 0; m < H; ++m) {
                const float cm = cmat[r][m];
                zx += cm * w2j[m].x;
                zy += cm * w2j[m].y;
                zz += cm * w2j[m].z;
                zw += cm * w2j[m].w;
            }
            if (i >= jj && i < jj + 4) {
                if      (i == jj + 0) zx += FEPS;
                else if (i == jj + 1) zy += FEPS;
                else if (i == jj + 2) zz += FEPS;
                else                  zw += FEPS;
            }
            *reinterpret_cast<float4*>(Z + (size_t)i * NO + jj) =
                make_float4(zx, zy, zz, zw);
        }
    }
}

extern "C" void kernel_launch(void* const* d_in, const int* in_sizes, int n_in,
                              void* d_out, int out_size, void* d_ws, size_t ws_size,
                              hipStream_t stream) {
    const float* X  = (const float*)d_in[0];
    const float* W1 = (const float*)d_in[1];
    const float* W2 = (const float*)d_in[2];
    float* out = (float*)d_out;
    float* ws  = (float*)d_ws;

    float* Mp = ws;   // NBLK*25 floats

    hipLaunchKernelGGL(k_xw1, dim3(NBLK), dim3(256), 0, stream, X, W1, Mp);
    hipLaunchKernelGGL(k_out, dim3(NCON), dim3(256), 0, stream, Mp, W2, out);
}

// Round 17
// 52.504 us; speedup vs baseline: 1.2369x; 1.2369x over previous
//
#include <hip/hip_runtime.h>
#include <math.h>

static constexpr int N    = 4096;  // IN_SIZE
static constexpr int H    = 5;     // HID
static constexpr int NO   = 2048;  // OUT_SIZE
static constexpr float FEPS = 1e-4f;
static constexpr int NBLK = 2048;           // k_xw1 blocks (8/CU nominal)
static constexpr int ITER = (N * N / 4) / (NBLK * 256);  // 8 strided rows/thread
static constexpr int STRD = NBLK * 256;     // 524288 float4s = 512 rows
static constexpr int NCON = 256;            // k_out blocks
static constexpr int NR   = NO / NCON;      // 8 output rows per k_out block

#if __has_builtin(__builtin_amdgcn_rcpf)
__device__ __forceinline__ float frcp(float x) { return __builtin_amdgcn_rcpf(x); }
#else
__device__ __forceinline__ float frcp(float x) { return 1.0f / x; }
#endif
#if __has_builtin(__builtin_amdgcn_rsqf)
__device__ __forceinline__ float frsq(float x) { return __builtin_amdgcn_rsqf(x); }
#else
__device__ __forceinline__ float frsq(float x) { return 1.0f / sqrtf(x); }
#endif

__device__ __forceinline__ float wave_reduce(float v) {
#pragma unroll
    for (int o = 32; o > 0; o >>= 1) v += __shfl_down(v, o, 64);
    return v;
}

// K1: flat grid-stride partial of M[a][b] = sum_{i,j} W1[i,a] X[i,j] W1[j,b].
// 2048 blocks x 256 thr; thread's float4 index f = b*256+t + k*512K, k<8:
// SAME column j4=f%1024 every iteration (wf[20] loaded once), rows 512 apart
// (w1r block-uniform scalar loads). 8 independent X loads issued as one
// batch -> 8-deep MLP, at ~5 blocks/CU (=20 waves/CU) TLP. This is the
// fillBuffer-style geometry (high grid + trivial per-iteration body) that
// hits 6.7 TB/s on this chip.
__global__ __launch_bounds__(256) void k_xw1(const float* __restrict__ X,
                                             const float* __restrict__ W1,
                                             float* __restrict__ Mp) {
    const int b = blockIdx.x;
    const int t = threadIdx.x;
    const int rowbase = b >> 2;              // f0/1024: block-uniform row
    const int j4c = ((b & 3) << 8) | t;      // f0 % 1024: thread's column
    const float4* W14 = reinterpret_cast<const float4*>(W1);
    const float4* X4  = reinterpret_cast<const float4*>(X);

    float wf[20];
    {
        const float4 f0 = W14[5 * j4c + 0];
        const float4 f1 = W14[5 * j4c + 1];
        const float4 f2 = W14[5 * j4c + 2];
        const float4 f3 = W14[5 * j4c + 3];
        const float4 f4 = W14[5 * j4c + 4];
        wf[0]=f0.x;  wf[1]=f0.y;  wf[2]=f0.z;  wf[3]=f0.w;
        wf[4]=f1.x;  wf[5]=f1.y;  wf[6]=f1.z;  wf[7]=f1.w;
        wf[8]=f2.x;  wf[9]=f2.y;  wf[10]=f2.z; wf[11]=f2.w;
        wf[12]=f3.x; wf[13]=f3.y; wf[14]=f3.z; wf[15]=f3.w;
        wf[16]=f4.x; wf[17]=f4.y; wf[18]=f4.z; wf[19]=f4.w;
    }

    // one batch of 8 independent coalesced X loads (compile-time offsets)
    const size_t f0i = (size_t)b * 256 + t;
    float4 xv[ITER];
#pragma unroll
    for (int k = 0; k < ITER; ++k)
        xv[k] = X4[f0i + (size_t)k * STRD];

    float pm[H][H];
#pragma unroll
    for (int a = 0; a < H; ++a)
#pragma unroll
        for (int bb = 0; bb < H; ++bb) pm[a][bb] = 0.f;

#pragma unroll
    for (int k = 0; k < ITER; ++k) {
        const int row = rowbase + k * 512;
        const float4 x = xv[k];
        float t5[H];
#pragma unroll
        for (int a = 0; a < H; ++a)
            t5[a] = x.x * wf[a]      + x.y * wf[5 + a]
                  + x.z * wf[10 + a] + x.w * wf[15 + a];
        float w1r[H];
#pragma unroll
        for (int a = 0; a < H; ++a) w1r[a] = W1[(size_t)row * H + a];
#pragma unroll
        for (int a = 0; a < H; ++a)
#pragma unroll
            for (int bb = 0; bb < H; ++bb) pm[a][bb] += w1r[a] * t5[bb];
    }

    __shared__ float sm[4][25];
    {
        const int lane = t & 63, wv = t >> 6;
#pragma unroll
        for (int a = 0; a < H; ++a)
#pragma unroll
            for (int bb = 0; bb < H; ++bb) {
                const float v = wave_reduce(pm[a][bb]);
                if (lane == 0) sm[wv][a * H + bb] = v;
            }
    }
    __syncthreads();
    if (t < 25)
        Mp[b * 25 + t] = sm[0][t] + sm[1][t] + sm[2][t] + sm[3][t];
}

// Lane-parallel Jacobi rotation, compile-time (p,q). Lane L (<25) holds
// a = A[L/5][L%5], u = U[L/5][L%5].
#define JROT(p, q)                                                            \
    {                                                                         \
        const float apq = __shfl(a, (p) * 5 + (q), 64);                       \
        const float app = __shfl(a, (p) * 5 + (p), 64);                       \
        const float aqq = __shfl(a, (q) * 5 + (q), 64);                       \
        const bool  skip =                                                    \
            (apq * apq) <= (1e-26f * (app * app + aqq * aqq) + 1e-38f);       \
        const float theta = (aqq - app) * frcp(2.0f * apq);                   \
        const float tden  = fabsf(theta) + sqrtf(theta * theta + 1.0f);       \
        const float ttv   = ((theta >= 0.0f) ? 1.0f : -1.0f) * frcp(tden);    \
        float cc = frsq(ttv * ttv + 1.0f);                                    \
        float ss = ttv * cc;                                                  \
        cc = skip ? 1.0f : cc;                                                \
        ss = skip ? 0.0f : ss;                                                \
        {                                                                     \
            const int  pr   = ((r == (p)) ? (q) : ((r == (q)) ? (p) : r));    \
            const float prt = __shfl(a, pr * 5 + c, 64);                      \
            a = (r == (p)) ? (cc * a - ss * prt)                              \
                           : ((r == (q)) ? (ss * prt + cc * a) : a);          \
        }                                                                     \
        {                                                                     \
            const int  pc   = ((c == (p)) ? (q) : ((c == (q)) ? (p) : c));    \
            const float prt = __shfl(a, r * 5 + pc, 64);                      \
            a = (c == (p)) ? (cc * a - ss * prt)                              \
                           : ((c == (q)) ? (ss * prt + cc * a) : a);          \
            const float urt = __shfl(u, r * 5 + pc, 64);                      \
            u = (c == (p)) ? (cc * u - ss * urt)                              \
                           : ((c == (q)) ? (ss * urt + cc * u) : u);          \
        }                                                                     \
    }

// K2: 256 blocks, NR=8 output rows each. Redundant reduce+Jacobi per block
// (concurrent across blocks -> hidden), then streaming W2 -> Z epilogue.
__global__ __launch_bounds__(256) void k_out(const float* __restrict__ Mp,
                                             const float* __restrict__ W2,
                                             float* __restrict__ Z) {
    __shared__ float sred[10][26];
    __shared__ float Msum[25];
    __shared__ float ys[25];
    const int t = threadIdx.x;

    if (t < 250) {
        const int e = t % 25, g = t / 25;
        float s = 0.f;
#pragma unroll 8
        for (int p = g; p < NBLK; p += 10) s += Mp[p * 25 + e];
        sred[g][e] = s;
    }
    __syncthreads();
    if (t < 25) {
        float s = 0.f;
#pragma unroll
        for (int g = 0; g < 10; ++g) s += sred[g][t];
        Msum[t] = s;
    }
    __syncthreads();

    if (t < 64) {
        const int r = t / 5, c = t % 5;
        const float m = (t < 25) ? Msum[t] : 0.f;
        float a = 0.f;
#pragma unroll
        for (int k = 0; k < H; ++k)
            a += __shfl(m, r * 5 + k, 64) * __shfl(m, c * 5 + k, 64);
        float u = (t < 25 && r == c) ? 1.0f : 0.0f;

        for (int sweep = 0; sweep < 6; ++sweep) {
            JROT(0, 1) JROT(0, 2) JROT(0, 3) JROT(0, 4) JROT(1, 2)
            JROT(1, 3) JROT(1, 4) JROT(2, 3) JROT(2, 4) JROT(3, 4)
        }

        const float ev = fmaxf(sqrtf(fmaxf(a, 0.0f)), FEPS);
        float yv = 0.f;
#pragma unroll
        for (int k = 0; k < H; ++k) {
            const float evk = __shfl(ev, 6 * k, 64);
            const float urk = __shfl(u, r * 5 + k, 64);
            const float uck = __shfl(u, c * 5 + k, 64);
            yv += evk * urk * uck;
        }
        if (t < 25) ys[t] = yv - ((r == c) ? FEPS : 0.f);
    }
    __syncthreads();

    const int i0 = blockIdx.x * NR;
    float cmat[NR][H];
#pragma unroll
    for (int r = 0; r < NR; ++r) {
        float wcol[H];
#pragma unroll
        for (int k = 0; k < H; ++k) wcol[k] = W2[(size_t)k * NO + i0 + r];
#pragma unroll
        for (int m = 0; m < H; ++m) {
            float s = 0.f;
#pragma unroll
            for (int k = 0; k < H; ++k) s += wcol[k] * ys[k * H + m];
            cmat[r][m] = s;
        }
    }

#pragma unroll
    for (int hh = 0; hh < 2; ++hh) {
        const int jj = (hh * 256 + t) * 4;
        float4 w2j[H];
#pragma unroll
        for (int m = 0; m < H; ++m)
            w2j[m] = *reinterpret_cast<const float4*>(W2 + (size_t)m * NO + jj);
#pragma unroll
        for (int r = 0; r < NR; ++r) {
            const int i = i0 + r;
            float zx = 0.f, zy = 0.f, zz = 0.f, zw = 0.f;
#pragma unroll
            for (int m = 0; m < H; ++m) {
                const float cm = cmat[r][m];
                zx += cm * w2j[m].x;
                zy += cm * w2j[m].y;
                zz += cm * w2j[m].z;
                zw += cm * w2j[m].w;
            }
            if (i >= jj && i < jj + 4) {
                if      (i == jj + 0) zx += FEPS;
                else if (i == jj + 1) zy += FEPS;
                else if (i == jj + 2) zz += FEPS;
                else                  zw += FEPS;
            }
            *reinterpret_cast<float4*>(Z + (size_t)i * NO + jj) =
                make_float4(zx, zy, zz, zw);
        }
    }
}

extern "C" void kernel_launch(void* const* d_in, const int* in_sizes, int n_in,
                              void* d_out, int out_size, void* d_ws, size_t ws_size,
                              hipStream_t stream) {
    const float* X  = (const float*)d_in[0];
    const float* W1 = (const float*)d_in[1];
    const float* W2 = (const float*)d_in[2];
    float* out = (float*)d_out;
    float* ws  = (float*)d_ws;

    float* Mp = ws;   // NBLK*25 floats (205 KB)

    hipLaunchKernelGGL(k_xw1, dim3(NBLK), dim3(256), 0, stream, X, W1, Mp);
    hipLaunchKernelGGL(k_out, dim3(NCON), dim3(256), 0, stream, Mp, W2, out);
}